// Round 17
// baseline (123.062 us; speedup 1.0000x reference)
//
#include <hip/hip_runtime.h>
#include <hip/hip_bf16.h>

// DisenGCN forward — SINGLE kernel, 16 blocks (8/side) x 1024 threads.
// Block bg owns neighbor rows {bg*128 + t + m*1024 : t<128, m<4} (512 rows),
// which are PRIVATE to it across all 6 routing sweeps. So:
//   prologue: gather + proj(W0) of my 512 rows -> LDS zB (raw bf16, padded
//             stride 80 shorts = 2-way-free banks); row-0 ego computed
//             redundantly per block; restage sW with W1.
//   sweeps 0..2: route on zB (normalize on the fly) -> R14 slot protocol
//             (u64{f32,gen32} atomicExch write / RMW gen-poll read, SPB=8).
//   at s==2: in-place W1 transform of zB (write normalized z1) in the sync
//             gap; row-0 proj(W1) from routed-L0 sum.
//   sweeps 3..5: route on prenormalized zB. s==5: block 0 polls all 16
//             partials and finalizes out.
// No K1, no dispatch boundary, no global znb buffers.
//
// Replay safety: slots gen-tagged; gen from per-block ctr via atomicAdd
// RETURN value (each block bumps its own ctr once per launch -> all blocks
// agree forever, incl. 0xAA-poisoned start). No ws zeroing needed.
//
// ws: slots[6*2*SPB*64 u64] | ctr[16 u32]

#define EPS 1e-12f
#define LOG2E 1.44269504088896f
#define SPB 8
#define NBK (2 * SPB)
#define ZSTR 80            // LDS row stride in shorts (160 B, 16B-aligned)

__device__ __forceinline__ float g16sum(float v) {
    v += __shfl_xor(v, 1, 64);
    v += __shfl_xor(v, 2, 64);
    v += __shfl_xor(v, 4, 64);
    v += __shfl_xor(v, 8, 64);
    return v;
}
__device__ __forceinline__ unsigned short f2bf(float f) {  // RNE
    unsigned int b = __float_as_uint(f);
    b += 0x7fffu + ((b >> 16) & 1u);
    return (unsigned short)(b >> 16);
}
__device__ __forceinline__ float bf2f(unsigned short u) {
    return __uint_as_float(((unsigned int)u) << 16);
}
__device__ __forceinline__ float bflo(unsigned int w) {
    return __uint_as_float(w << 16);
}
__device__ __forceinline__ float bfhi(unsigned int w) {
    return __uint_as_float(w & 0xffff0000u);
}
__device__ __forceinline__ void slot_write(unsigned long long* p, float v,
                                           unsigned int gen) {
    atomicExch(p, ((unsigned long long)__float_as_uint(v) << 32) |
                  (unsigned long long)gen);
}
__device__ __forceinline__ float slot_read(unsigned long long* p,
                                           unsigned int gen) {
    unsigned long long v;
    for (;;) {
        v = atomicAdd(p, 0ull);
        if ((unsigned int)(v & 0xffffffffull) == gen) break;
        __builtin_amdgcn_s_sleep(1);
    }
    return __uint_as_float((unsigned int)(v >> 32));
}

__global__ __launch_bounds__(1024, 1) void disen_one(
    const int* __restrict__ user, const int* __restrict__ item,
    const int* __restrict__ nu, const int* __restrict__ ni,
    const float* __restrict__ Gu, const float* __restrict__ Gi,
    const float* __restrict__ W0, const float* __restrict__ b0,
    const float* __restrict__ W1, const float* __restrict__ b1,
    unsigned long long* __restrict__ slots, unsigned int* __restrict__ ctr,
    float* __restrict__ out, int n_neigh)
{
    const int tid  = threadIdx.x;
    const int lane = tid & 63;
    const int wv   = tid >> 6;
    const int side = blockIdx.x & 1;
    const int bg   = blockIdx.x >> 1;
    const int g    = lane >> 4;     // 16-lane group (row-in-chunk for proj)
    const int c    = lane & 15;     // chunk index (proj layout)
    const int j    = lane & 7;      // octet index (route layout)

    __shared__ float sW[4096];             // i-major: sW[i*64 + m]
    __shared__ float red[16][64];
    __shared__ float sEgo[64];
    __shared__ float sTmp[64];
    __shared__ unsigned int sGen;
    __shared__ unsigned short zB[512 * ZSTR];   // my 512 rows, bf16

    if (tid == 0) sGen = (atomicAdd(&ctr[blockIdx.x], 1u) + 1u) * 8u;

    // ---- stage W0 (i-major) ----
    for (int q = tid; q < 4096; q += 1024) {
        const int i = q >> 6, m = q & 63;
        sW[q] = W0[(m >> 4) * 1024 + i * 16 + (m & 15)];
    }
    __syncthreads();
    const unsigned int genbase = sGen;

    // ---- prologue: gather my 512 rows (8 prefetched passes of 4 rows/wave) ----
    const int*   nidx = side ? ni : nu;
    const float* G    = side ? Gu : Gi;
    float4 xv[8];
#pragma unroll
    for (int pass = 0; pass < 8; ++pass) {
        const int L = pass * 64 + wv * 4 + g;
        const int n = 1 + bg * 128 + (L & 127) + (L >> 7) * (SPB * 128);
        if (n <= n_neigh)
            xv[pass] = ((const float4*)(G + (size_t)nidx[n - 1] * 64))[c];
        else
            xv[pass] = make_float4(0.f, 0.f, 0.f, 0.f);
    }
    // ---- proj(W0) -> zB raw bf16 ----
    {
        const float4 bv = ((const float4*)b0)[c];
#pragma unroll
        for (int pass = 0; pass < 8; ++pass) {
            const int L = pass * 64 + wv * 4 + g;
            const bool act = (1 + bg * 128 + (L & 127) + (L >> 7) * (SPB * 128)) <= n_neigh;
            float xa[4] = {xv[pass].x, xv[pass].y, xv[pass].z, xv[pass].w};
            float o0 = bv.x, o1 = bv.y, o2 = bv.z, o3 = bv.w;
#pragma unroll
            for (int i = 0; i < 64; ++i) {
                const float xi = __shfl(xa[i & 3], (g << 4) + (i >> 2), 64);
                const float4 w = ((const float4*)sW)[i * 16 + c];
                o0 = fmaf(xi, w.x, o0); o1 = fmaf(xi, w.y, o1);
                o2 = fmaf(xi, w.z, o2); o3 = fmaf(xi, w.w, o3);
            }
            ushort4 st;
            if (act) {
                st.x = f2bf(fmaxf(o0, 0.f)); st.y = f2bf(fmaxf(o1, 0.f));
                st.z = f2bf(fmaxf(o2, 0.f)); st.w = f2bf(fmaxf(o3, 0.f));
            } else st = make_ushort4(0, 0, 0, 0);
            *(ushort4*)&zB[L * ZSTR + 4 * c] = st;
        }
    }
    // ---- row-0 ego (redundant per block, wave 0) ----
    if (wv == 0) {
        const int idx0 = side ? item[0] : user[0];
        const float* G0 = side ? Gi : Gu;
        const float4 q0 = ((const float4*)(G0 + (size_t)idx0 * 64))[c];
        float xa[4] = {q0.x, q0.y, q0.z, q0.w};
        float s = b0[lane];
#pragma unroll
        for (int i = 0; i < 64; ++i)
            s = fmaf(__shfl(xa[i & 3], i >> 2, 64), sW[i * 64 + lane], s);
        s = fmaxf(s, 0.f);
        sEgo[lane] = (s / fmaxf(sqrtf(g16sum(s * s)), EPS)) * LOG2E;
    }
    __syncthreads();                       // zB + ego done; sW free
    // ---- restage sW with W1 (needed at s==2) ----
    for (int q = tid; q < 4096; q += 1024) {
        const int i = q >> 6, m = q & 63;
        sW[q] = W1[(m >> 4) * 1024 + i * 16 + (m & 15)];
    }
    __syncthreads();

    // ---- 6 routing sweeps ----
    for (int s = 0; s < 6; ++s) {
        const unsigned int gen = genbase + (unsigned int)s + 1u;
        float ego[8];
#pragma unroll
        for (int m = 0; m < 8; ++m) ego[m] = sEgo[j * 8 + m];

        float a8[8] = {0.f, 0.f, 0.f, 0.f, 0.f, 0.f, 0.f, 0.f};
#pragma unroll
        for (int m = 0; m < 4; ++m) {
            const int L = m * 128 + (tid >> 3);
            const uint4 q = *(const uint4*)&zB[L * ZSTR + 8 * j];
            float x[8];
            x[0] = bflo(q.x); x[1] = bfhi(q.x);
            x[2] = bflo(q.y); x[3] = bfhi(q.y);
            x[4] = bflo(q.z); x[5] = bfhi(q.z);
            x[6] = bflo(q.w); x[7] = bfhi(q.w);
            float inv = 1.f;
            if (s < 3) {                    // zB holds RAW z0: normalize on the fly
                float ss = 0.f;
#pragma unroll
                for (int mm = 0; mm < 8; ++mm) ss = fmaf(x[mm], x[mm], ss);
                ss += __shfl_xor(ss, 1, 64);
                inv = __builtin_amdgcn_rcpf(fmaxf(sqrtf(ss), EPS));
            }
            float partial = 0.f;
#pragma unroll
            for (int mm = 0; mm < 8; ++mm) partial = fmaf(x[mm], ego[mm], partial);
            const float dp = (partial + __shfl_xor(partial, 1, 64)) * inv;
            const float eo = exp2f(dp);
            float den = eo + __shfl_xor(eo, 2, 64);
            den += __shfl_xor(den, 4, 64);
            const float p = eo * __builtin_amdgcn_rcpf(den) * inv;
#pragma unroll
            for (int mm = 0; mm < 8; ++mm) a8[mm] = fmaf(p, x[mm], a8[mm]);
        }
#pragma unroll
        for (int mask = 8; mask <= 32; mask <<= 1)
#pragma unroll
            for (int m = 0; m < 8; ++m) a8[m] += __shfl_xor(a8[m], mask, 64);
        if (lane < 8) {
#pragma unroll
            for (int m = 0; m < 8; ++m) red[wv][lane * 8 + m] = a8[m];
        }
        __syncthreads();                              // (1) red complete

        unsigned long long* slotbase = slots + (size_t)(s * 2 + side) * SPB * 64;
        if (wv == 0) {
            float ssum = 0.f;
#pragma unroll
            for (int w = 0; w < 16; ++w) ssum += red[w][lane];
            slot_write(&slotbase[bg * 64 + lane], ssum, gen);
        }
        __syncthreads();                              // (2) red reusable

        if (s == 2) {
            // ---- in-place W1 transform of my rows (hidden in sync gap) ----
            const float4 bv1 = ((const float4*)b1)[c];
#pragma unroll
            for (int pass = 0; pass < 8; ++pass) {
                const int L = pass * 64 + wv * 4 + g;
                const bool act = (1 + bg * 128 + (L & 127) + (L >> 7) * (SPB * 128)) <= n_neigh;
                const ushort4 u = *(const ushort4*)&zB[L * ZSTR + 4 * c];
                float xa[4] = {bf2f(u.x), bf2f(u.y), bf2f(u.z), bf2f(u.w)};
                float o0 = bv1.x, o1 = bv1.y, o2 = bv1.z, o3 = bv1.w;
#pragma unroll
                for (int i = 0; i < 64; ++i) {
                    const float xi = __shfl(xa[i & 3], (g << 4) + (i >> 2), 64);
                    const float4 w = ((const float4*)sW)[i * 16 + c];
                    o0 = fmaf(xi, w.x, o0); o1 = fmaf(xi, w.y, o1);
                    o2 = fmaf(xi, w.z, o2); o3 = fmaf(xi, w.w, o3);
                }
                o0 = fmaxf(o0, 0.f); o1 = fmaxf(o1, 0.f);
                o2 = fmaxf(o2, 0.f); o3 = fmaxf(o3, 0.f);
                float ss = o0 * o0 + o1 * o1 + o2 * o2 + o3 * o3;
                ss += __shfl_xor(ss, 1, 64);
                ss += __shfl_xor(ss, 2, 64);          // 16-elem channel norm
                const float inv = __builtin_amdgcn_rcpf(fmaxf(sqrtf(ss), EPS));
                ushort4 st;
                if (act) {
                    st.x = f2bf(o0 * inv); st.y = f2bf(o1 * inv);
                    st.z = f2bf(o2 * inv); st.w = f2bf(o3 * inv);
                } else st = make_ushort4(0, 0, 0, 0);
                *(ushort4*)&zB[L * ZSTR + 4 * c] = st;   // normalized z1
            }
        }

        if (s < 5) {
            if (wv < SPB)
                red[wv][lane] = slot_read(&slotbase[wv * 64 + lane], gen);
            __syncthreads();                          // (3) partials in LDS
            if (wv == 0) {
                float e = 0.f;
#pragma unroll
                for (int bb = 0; bb < SPB; ++bb) e += red[bb][lane];
                if (s == 2) sTmp[lane] = e;           // raw routed L0
                else sEgo[lane] = (e / fmaxf(sqrtf(g16sum(e * e)), EPS)) * LOG2E;
            }
            __syncthreads();                          // (4)
            if (s == 2) {
                if (wv == 0) {                        // row-0 proj(W1)
                    float xa[4];
#pragma unroll
                    for (int jj = 0; jj < 4; ++jj) xa[jj] = sTmp[((lane & 15) << 2) | jj];
                    float sum = b1[lane];
#pragma unroll
                    for (int i = 0; i < 64; ++i)
                        sum = fmaf(__shfl(xa[i & 3], i >> 2, 64), sW[i * 64 + lane], sum);
                    sum = fmaxf(sum, 0.f);
                    sEgo[lane] = (sum / fmaxf(sqrtf(g16sum(sum * sum)), EPS)) * LOG2E;
                }
                __syncthreads();                      // (5)
            }
        } else if (blockIdx.x == 0) {
            // finalize: 16 waves poll all 16 s=5 partials (both sides)
            const int s2 = wv >> 3, bb = wv & 7;
            unsigned long long* sb2 = slots + (size_t)(5 * 2 + s2) * SPB * 64;
            red[wv][lane] = slot_read(&sb2[bb * 64 + lane], gen);
            __syncthreads();
            if (wv == 0) {
                float u = 0.f, v = 0.f;
#pragma unroll
                for (int w = 0; w < 8; ++w)  u += red[w][lane];
#pragma unroll
                for (int w = 8; w < 16; ++w) v += red[w][lane];
                out[1 + lane]  = u;
                out[65 + lane] = v;
                float p = u * v;
#pragma unroll
                for (int sh = 32; sh >= 1; sh >>= 1) p += __shfl_xor(p, sh, 64);
                if (lane == 0) out[0] = p;
            }
        }
    }
}

extern "C" void kernel_launch(void* const* d_in, const int* in_sizes, int n_in,
                              void* d_out, int out_size, void* d_ws, size_t ws_size,
                              hipStream_t stream) {
    const int*   user       = (const int*)d_in[0];
    const int*   item       = (const int*)d_in[1];
    const int*   neigh_user = (const int*)d_in[2];
    const int*   neigh_item = (const int*)d_in[3];
    const float* Gu         = (const float*)d_in[4];
    const float* Gi         = (const float*)d_in[5];
    const float* W0         = (const float*)d_in[6];
    const float* b0         = (const float*)d_in[7];
    const float* W1         = (const float*)d_in[8];
    const float* b1         = (const float*)d_in[9];
    float* out = (float*)d_out;

    const int n_neigh = in_sizes[2];

    unsigned long long* slots = (unsigned long long*)d_ws;
    unsigned int*       ctr   = (unsigned int*)(slots + 6 * 2 * SPB * 64);

    hipLaunchKernelGGL(disen_one, dim3(NBK), dim3(1024), 0, stream,
                       user, item, neigh_user, neigh_item, Gu, Gi,
                       W0, b0, W1, b1, slots, ctr, out, n_neigh);
}

// Round 18
// 41.086 us; speedup vs baseline: 2.9952x; 2.9952x over previous
//
#include <hip/hip_runtime.h>
#include <hip/hip_bf16.h>

// DisenGCN forward — 2-dispatch chain (best-known R14 structure), fast K1:
//   K1 (chip-wide, 4 rows/wave chunk-layout): gather -> z0=proj(W0) -> znbA
//       [bf16 norm]; neighbors also z1=proj(W1,z0) -> znbB [bf16 norm].
//       Bumps call_ctr.
//   K2 (16 blocks = 8/side x 1024 thr): 6 routing sweeps, gen-tagged u64
//       {f32 payload, gen32} slots: write = one atomicExch, read = RMW-poll
//       until gen matches (payload rides the poll). No fences/flags/zeroing.
//       s==2: row-0 proj(W1). s==5: block(0,0) polls all 16 partials, final.
//
// K1 chunk layout: wave handles 4 combined rows; lane (g=lane>>4, c=lane&15)
// holds row (base+g)'s elems 4c..4c+3. One 64-iter loop projects 4 rows:
// xi = shfl(xa[i&3], (g<<4)+(i>>2)); W float4 = W[k][i][4(c&3)..+3], k=c>>2.
// proj1 consumes raw relu'd z0 in-register (no regroup).
//
// Route layout (K2): 8 lanes/row; lane j=lane&7 holds elems [8j..8j+7];
// channel k=j>>1. Ego normalized AND pre-scaled by log2(e) (exp2 softmax).
//
// ws: znbA[2*n_rows*64 bf16] | znbB[same] | slots[6*2*SPB*64 u64] | call_ctr

#define EPS 1e-12f
#define LOG2E 1.44269504088896f
#define SPB 8              // blocks per side in K2
#define NBK (2 * SPB)

__device__ __forceinline__ float g16sum(float v) {
    v += __shfl_xor(v, 1, 64);
    v += __shfl_xor(v, 2, 64);
    v += __shfl_xor(v, 4, 64);
    v += __shfl_xor(v, 8, 64);
    return v;
}
__device__ __forceinline__ unsigned short f2bf(float f) {  // RNE
    unsigned int b = __float_as_uint(f);
    b += 0x7fffu + ((b >> 16) & 1u);
    return (unsigned short)(b >> 16);
}
__device__ __forceinline__ float bf2f(unsigned short u) {
    return __uint_as_float(((unsigned int)u) << 16);
}
__device__ __forceinline__ float bflo(unsigned int w) {
    return __uint_as_float(w << 16);
}
__device__ __forceinline__ float bfhi(unsigned int w) {
    return __uint_as_float(w & 0xffff0000u);
}

__device__ __forceinline__ void slot_write(unsigned long long* p, float v,
                                           unsigned int gen) {
    atomicExch(p, ((unsigned long long)__float_as_uint(v) << 32) |
                  (unsigned long long)gen);
}
__device__ __forceinline__ float slot_read(unsigned long long* p,
                                           unsigned int gen) {
    unsigned long long v;
    for (;;) {
        v = atomicAdd(p, 0ull);                       // 64-bit RMW read
        if ((unsigned int)(v & 0xffffffffull) == gen) break;
        __builtin_amdgcn_s_sleep(1);
    }
    return __uint_as_float((unsigned int)(v >> 32));
}

// ---- K1: gather + proj L0 + (neighbors) proj L1; 4 rows/wave ----
__global__ __launch_bounds__(256) void k1_gather_proj2(
    const int* __restrict__ user, const int* __restrict__ item,
    const int* __restrict__ nu, const int* __restrict__ ni,
    const float* __restrict__ Gu, const float* __restrict__ Gi,
    const float* __restrict__ W0, const float* __restrict__ b0,
    const float* __restrict__ W1, const float* __restrict__ b1,
    unsigned short* __restrict__ znbA, unsigned short* __restrict__ znbB,
    unsigned int* __restrict__ call_ctr, int n_rows)
{
    if (blockIdx.x == 0 && threadIdx.x == 0) atomicAdd(call_ctr, 1u);

    const int lane = threadIdx.x & 63;
    const int wv   = threadIdx.x >> 6;
    const int g    = lane >> 4;      // row-in-quad
    const int c    = lane & 15;      // chunk (elems 4c..4c+3)
    const int base = (blockIdx.x * 4 + wv) * 4;
    if (base >= 2 * n_rows) return;
    const int rr   = base + g;
    const bool act = rr < 2 * n_rows;
    const int side = act ? (rr >= n_rows) : 0;
    const int n    = act ? (rr - side * n_rows) : 0;

    // gather my row's chunk (4 rows of the wave gathered concurrently)
    float xa[4] = {0.f, 0.f, 0.f, 0.f};
    if (act) {
        int idx; const float* G;
        if (n == 0) { idx = side ? item[0] : user[0];     G = side ? Gi : Gu; }
        else        { idx = side ? ni[n - 1] : nu[n - 1]; G = side ? Gu : Gi; }
        const float4 xv = ((const float4*)(G + (size_t)idx * 64))[c];
        xa[0] = xv.x; xa[1] = xv.y; xa[2] = xv.z; xa[3] = xv.w;
    }

    const int k = c >> 2;
    // ---- proj(W0): 4 rows in one loop ----
    const float4 bv0 = ((const float4*)b0)[c];
    float o[4] = {bv0.x, bv0.y, bv0.z, bv0.w};
    {
        const float4* __restrict__ Wp = (const float4*)(W0 + k * 1024) + (c & 3);
#pragma unroll
        for (int i = 0; i < 64; ++i) {
            const float xi = __shfl(xa[i & 3], (g << 4) + (i >> 2), 64);
            const float4 w = Wp[i * 4];
            o[0] = fmaf(xi, w.x, o[0]); o[1] = fmaf(xi, w.y, o[1]);
            o[2] = fmaf(xi, w.z, o[2]); o[3] = fmaf(xi, w.w, o[3]);
        }
    }
#pragma unroll
    for (int q = 0; q < 4; ++q) o[q] = fmaxf(o[q], 0.f);
    {   // channel norm (16 elems = my quad of lanes)
        float ss = o[0] * o[0] + o[1] * o[1] + o[2] * o[2] + o[3] * o[3];
        ss += __shfl_xor(ss, 1, 64);
        ss += __shfl_xor(ss, 2, 64);
        const float inv = 1.f / fmaxf(sqrtf(ss), EPS);
        if (act) {
            ushort4 st;
            st.x = f2bf(o[0] * inv); st.y = f2bf(o[1] * inv);
            st.z = f2bf(o[2] * inv); st.w = f2bf(o[3] * inv);
            *(ushort4*)&znbA[(size_t)rr * 64 + 4 * c] = st;
        }
    }

    // ---- proj(W1) on raw z0 (neighbors only; row 0 handled in K2) ----
    const float4 bv1 = ((const float4*)b1)[c];
    float p[4] = {bv1.x, bv1.y, bv1.z, bv1.w};
    {
        const float4* __restrict__ Wp = (const float4*)(W1 + k * 1024) + (c & 3);
#pragma unroll
        for (int i = 0; i < 64; ++i) {
            const float xi = __shfl(o[i & 3], (g << 4) + (i >> 2), 64);
            const float4 w = Wp[i * 4];
            p[0] = fmaf(xi, w.x, p[0]); p[1] = fmaf(xi, w.y, p[1]);
            p[2] = fmaf(xi, w.z, p[2]); p[3] = fmaf(xi, w.w, p[3]);
        }
    }
#pragma unroll
    for (int q = 0; q < 4; ++q) p[q] = fmaxf(p[q], 0.f);
    {
        float ss = p[0] * p[0] + p[1] * p[1] + p[2] * p[2] + p[3] * p[3];
        ss += __shfl_xor(ss, 1, 64);
        ss += __shfl_xor(ss, 2, 64);
        const float inv = 1.f / fmaxf(sqrtf(ss), EPS);
        if (act && n > 0) {
            ushort4 st;
            st.x = f2bf(p[0] * inv); st.y = f2bf(p[1] * inv);
            st.z = f2bf(p[2] * inv); st.w = f2bf(p[3] * inv);
            *(ushort4*)&znbB[(size_t)rr * 64 + 4 * c] = st;
        }
    }
}

// ---- K2: 6 routing sweeps across 8 blocks/side + fused finalize ----
__global__ __launch_bounds__(1024) void k2_route_all(
    const unsigned short* __restrict__ znbA, const unsigned short* __restrict__ znbB,
    const float* __restrict__ W1, const float* __restrict__ b1,
    unsigned long long* __restrict__ slots,
    const unsigned int* __restrict__ call_ctr,
    float* __restrict__ out, int n_neigh)
{
    const int n_rows = n_neigh + 1;
    const int tid  = threadIdx.x;
    const int lane = tid & 63;
    const int wv   = tid >> 6;
    const int side = blockIdx.x & 1;
    const int bg   = blockIdx.x >> 1;
    const unsigned short* __restrict__ zA = znbA + (size_t)side * n_rows * 64;
    const unsigned short* __restrict__ zB = znbB + (size_t)side * n_rows * 64;
    const unsigned int genbase = (*call_ctr) * 8u;   // dispatch-boundary read

    __shared__ float sW[4096];   // W1 i-major: sW[i*64 + m]
    __shared__ float red[16][64];
    __shared__ float sEgo[64];
    __shared__ float sTmp[64];

    for (int q = tid; q < 4096; q += 1024) {
        const int i = q >> 6, m = q & 63;
        sW[q] = W1[(m >> 4) * 1024 + i * 16 + (m & 15)];
    }
    if (tid < 64) sEgo[tid] = bf2f(zA[tid]) * LOG2E;  // normalized row 0
    __syncthreads();

    const int j   = lane & 7;
    const int rg0 = bg * 128 + (tid >> 3);   // this block's first row offset

    for (int s = 0; s < 6; ++s) {
        const unsigned short* __restrict__ zb = (s < 3) ? zA : zB;
        const unsigned int gen = genbase + (unsigned int)s + 1u;
        float ego[8];
#pragma unroll
        for (int m = 0; m < 8; ++m) ego[m] = sEgo[j * 8 + m];

        float a8[8] = {0.f, 0.f, 0.f, 0.f, 0.f, 0.f, 0.f, 0.f};
        for (int r = rg0; r < n_neigh; r += SPB * 128) {
            const uint4 q = *(const uint4*)(zb + (((size_t)r + 1) << 6) + (j << 3));
            float x[8];
            x[0] = bflo(q.x); x[1] = bfhi(q.x);
            x[2] = bflo(q.y); x[3] = bfhi(q.y);
            x[4] = bflo(q.z); x[5] = bfhi(q.z);
            x[6] = bflo(q.w); x[7] = bfhi(q.w);
            float partial = 0.f;
#pragma unroll
            for (int m = 0; m < 8; ++m) partial = fmaf(x[m], ego[m], partial);
            const float dp = partial + __shfl_xor(partial, 1, 64);  // ch dot * log2e
            const float eo = exp2f(dp);
            float den = eo + __shfl_xor(eo, 2, 64);
            den += __shfl_xor(den, 4, 64);                          // all 4 channels
            const float p = eo * __builtin_amdgcn_rcpf(den);
#pragma unroll
            for (int m = 0; m < 8; ++m) a8[m] = fmaf(p, x[m], a8[m]);
        }
#pragma unroll
        for (int mask = 8; mask <= 32; mask <<= 1)
#pragma unroll
            for (int m = 0; m < 8; ++m) a8[m] += __shfl_xor(a8[m], mask, 64);
        if (lane < 8) {
#pragma unroll
            for (int m = 0; m < 8; ++m) red[wv][lane * 8 + m] = a8[m];
        }
        __syncthreads();                                  // (1) red complete

        unsigned long long* slotbase = slots + (size_t)(s * 2 + side) * SPB * 64;
        if (wv == 0) {
            float ssum = 0.f;
#pragma unroll
            for (int w = 0; w < 16; ++w) ssum += red[w][lane];
            slot_write(&slotbase[bg * 64 + lane], ssum, gen);  // one exch
        }
        __syncthreads();                                  // (2) red reusable

        if (s < 5) {
            if (wv < SPB)
                red[wv][lane] = slot_read(&slotbase[wv * 64 + lane], gen);
            __syncthreads();                              // (3) partials in LDS
            if (wv == 0) {
                float e = 0.f;
#pragma unroll
                for (int bb = 0; bb < SPB; ++bb) e += red[bb][lane];
                if (s == 2) sTmp[lane] = e;               // raw routed L0
                else sEgo[lane] = (e / fmaxf(sqrtf(g16sum(e * e)), EPS)) * LOG2E;
            }
            __syncthreads();                              // (4) ego ready
            if (s == 2) {
                if (wv == 0) {                            // row-0 proj(W1)
                    float xa[4];
#pragma unroll
                    for (int jj = 0; jj < 4; ++jj) xa[jj] = sTmp[((lane & 15) << 2) | jj];
                    float sum = b1[lane];
#pragma unroll
                    for (int i = 0; i < 64; ++i)
                        sum = fmaf(__shfl(xa[i & 3], i >> 2, 64), sW[i * 64 + lane], sum);
                    sum = fmaxf(sum, 0.f);
                    sEgo[lane] = (sum / fmaxf(sqrtf(g16sum(sum * sum)), EPS)) * LOG2E;
                }
                __syncthreads();                          // (5)
            }
        } else if (side == 0 && bg == 0) {
            // finalize: 16 waves poll all 16 s=5 partials (both sides)
            const int s2 = wv >> 3, bb = wv & 7;
            unsigned long long* sb2 = slots + (size_t)(5 * 2 + s2) * SPB * 64;
            red[wv][lane] = slot_read(&sb2[bb * 64 + lane], gen);
            __syncthreads();
            if (wv == 0) {
                float u = 0.f, v = 0.f;
#pragma unroll
                for (int w = 0; w < 8; ++w)  u += red[w][lane];
#pragma unroll
                for (int w = 8; w < 16; ++w) v += red[w][lane];
                out[1 + lane]  = u;
                out[65 + lane] = v;
                float p = u * v;
#pragma unroll
                for (int sh = 32; sh >= 1; sh >>= 1) p += __shfl_xor(p, sh, 64);
                if (lane == 0) out[0] = p;
            }
        }
    }
}

extern "C" void kernel_launch(void* const* d_in, const int* in_sizes, int n_in,
                              void* d_out, int out_size, void* d_ws, size_t ws_size,
                              hipStream_t stream) {
    const int*   user       = (const int*)d_in[0];
    const int*   item       = (const int*)d_in[1];
    const int*   neigh_user = (const int*)d_in[2];
    const int*   neigh_item = (const int*)d_in[3];
    const float* Gu         = (const float*)d_in[4];
    const float* Gi         = (const float*)d_in[5];
    const float* W0         = (const float*)d_in[6];
    const float* b0         = (const float*)d_in[7];
    const float* W1         = (const float*)d_in[8];
    const float* b1         = (const float*)d_in[9];
    float* out = (float*)d_out;

    const int n_neigh = in_sizes[2];
    const int n_rows  = n_neigh + 1;
    const size_t rowsz = (size_t)2 * n_rows * 64;

    unsigned short*     znbA  = (unsigned short*)d_ws;
    unsigned short*     znbB  = znbA + rowsz;
    unsigned long long* slots = (unsigned long long*)(znbB + rowsz);
    unsigned int*       ctr   = (unsigned int*)(slots + 6 * 2 * SPB * 64);

    hipLaunchKernelGGL(k1_gather_proj2, dim3((2 * n_rows + 15) / 16), dim3(256), 0, stream,
                       user, item, neigh_user, neigh_item, Gu, Gi, W0, b0, W1, b1,
                       znbA, znbB, ctr, n_rows);
    hipLaunchKernelGGL(k2_route_all, dim3(NBK), dim3(1024), 0, stream,
                       znbA, znbB, W1, b1, slots, ctr, out, n_neigh);
}